// Round 9
// baseline (300.354 us; speedup 1.0000x reference)
//
#include <hip/hip_runtime.h>
#include <math.h>

// ParallelSMLSTMCell decomposed: never materialize C[B,S,D,D].
// B=8 S=512 F=32 D=64, window w=102. All f32.
// r9: k_ssm y-reduce folded into main reduce (3-way interleaved DPP chains
// s1/s2/s3 + precomputed S1/S2 tables; y = irs*(s3-mu*S1)+S2 computed post-
// chunk from cndmask-gathered mu/irs/s3). State kept pre-LN. k_proj/k_final/
// k_post reduction chains interleaved (dred2/3/4, dscan3).
#define BB 8
#define SS 512
#define FF 32
#define DD 64
#define WVOL 102
#define CH 16
#define NCH (SS / CH)  // 32 chunks

template<int CTRL, int RM, bool BC>
__device__ __forceinline__ float updpp(float oldv, float x) {
  return __int_as_float(__builtin_amdgcn_update_dpp(
      __float_as_int(oldv), __float_as_int(x), CTRL, RM, 0xF, BC));
}
__device__ __forceinline__ float rlane(float v, int l) {
  return __int_as_float(__builtin_amdgcn_readlane(__float_as_int(v), l));
}
__device__ __forceinline__ float dsum64(float x) {
  x += updpp<0x111, 0xF, true>(0.f, x);
  x += updpp<0x112, 0xF, true>(0.f, x);
  x += updpp<0x114, 0xF, true>(0.f, x);
  x += updpp<0x118, 0xF, true>(0.f, x);
  x += updpp<0x142, 0xF, true>(0.f, x);
  x += updpp<0x143, 0xF, true>(0.f, x);
  return rlane(x, 63);
}
// interleaved wave64 sums (broadcast results)
__device__ __forceinline__ void dred2(float& a, float& b) {
  a += updpp<0x111,0xF,true>(0.f,a); b += updpp<0x111,0xF,true>(0.f,b);
  a += updpp<0x112,0xF,true>(0.f,a); b += updpp<0x112,0xF,true>(0.f,b);
  a += updpp<0x114,0xF,true>(0.f,a); b += updpp<0x114,0xF,true>(0.f,b);
  a += updpp<0x118,0xF,true>(0.f,a); b += updpp<0x118,0xF,true>(0.f,b);
  a += updpp<0x142,0xF,true>(0.f,a); b += updpp<0x142,0xF,true>(0.f,b);
  a += updpp<0x143,0xF,true>(0.f,a); b += updpp<0x143,0xF,true>(0.f,b);
  a = rlane(a, 63); b = rlane(b, 63);
}
__device__ __forceinline__ void dred3(float& a, float& b, float& c) {
  a += updpp<0x111,0xF,true>(0.f,a); b += updpp<0x111,0xF,true>(0.f,b); c += updpp<0x111,0xF,true>(0.f,c);
  a += updpp<0x112,0xF,true>(0.f,a); b += updpp<0x112,0xF,true>(0.f,b); c += updpp<0x112,0xF,true>(0.f,c);
  a += updpp<0x114,0xF,true>(0.f,a); b += updpp<0x114,0xF,true>(0.f,b); c += updpp<0x114,0xF,true>(0.f,c);
  a += updpp<0x118,0xF,true>(0.f,a); b += updpp<0x118,0xF,true>(0.f,b); c += updpp<0x118,0xF,true>(0.f,c);
  a += updpp<0x142,0xF,true>(0.f,a); b += updpp<0x142,0xF,true>(0.f,b); c += updpp<0x142,0xF,true>(0.f,c);
  a += updpp<0x143,0xF,true>(0.f,a); b += updpp<0x143,0xF,true>(0.f,b); c += updpp<0x143,0xF,true>(0.f,c);
  a = rlane(a, 63); b = rlane(b, 63); c = rlane(c, 63);
}
__device__ __forceinline__ void dred4(float& a, float& b, float& c, float& d) {
  a += updpp<0x111,0xF,true>(0.f,a); b += updpp<0x111,0xF,true>(0.f,b); c += updpp<0x111,0xF,true>(0.f,c); d += updpp<0x111,0xF,true>(0.f,d);
  a += updpp<0x112,0xF,true>(0.f,a); b += updpp<0x112,0xF,true>(0.f,b); c += updpp<0x112,0xF,true>(0.f,c); d += updpp<0x112,0xF,true>(0.f,d);
  a += updpp<0x114,0xF,true>(0.f,a); b += updpp<0x114,0xF,true>(0.f,b); c += updpp<0x114,0xF,true>(0.f,c); d += updpp<0x114,0xF,true>(0.f,d);
  a += updpp<0x118,0xF,true>(0.f,a); b += updpp<0x118,0xF,true>(0.f,b); c += updpp<0x118,0xF,true>(0.f,c); d += updpp<0x118,0xF,true>(0.f,d);
  a += updpp<0x142,0xF,true>(0.f,a); b += updpp<0x142,0xF,true>(0.f,b); c += updpp<0x142,0xF,true>(0.f,c); d += updpp<0x142,0xF,true>(0.f,d);
  a += updpp<0x143,0xF,true>(0.f,a); b += updpp<0x143,0xF,true>(0.f,b); c += updpp<0x143,0xF,true>(0.f,c); d += updpp<0x143,0xF,true>(0.f,d);
  a = rlane(a, 63); b = rlane(b, 63); c = rlane(c, 63); d = rlane(d, 63);
}
// interleaved 32-lane sums (lanes 0-31; broadcast from lane 31)
__device__ __forceinline__ void dred2_32(float& a, float& b) {
  a += updpp<0x111,0xF,true>(0.f,a); b += updpp<0x111,0xF,true>(0.f,b);
  a += updpp<0x112,0xF,true>(0.f,a); b += updpp<0x112,0xF,true>(0.f,b);
  a += updpp<0x114,0xF,true>(0.f,a); b += updpp<0x114,0xF,true>(0.f,b);
  a += updpp<0x118,0xF,true>(0.f,a); b += updpp<0x118,0xF,true>(0.f,b);
  a += updpp<0x142,0xF,true>(0.f,a); b += updpp<0x142,0xF,true>(0.f,b);
  a = rlane(a, 31); b = rlane(b, 31);
}
// sum over the 16-lane DPP row; lane (row*16+15) holds the row sum
__device__ __forceinline__ float dsum16(float x) {
  x += updpp<0x111, 0xF, true>(0.f, x);
  x += updpp<0x112, 0xF, true>(0.f, x);
  x += updpp<0x114, 0xF, true>(0.f, x);
  x += updpp<0x118, 0xF, true>(0.f, x);
  return x;
}
// interleaved inclusive scans: f mul-scan, z/r add-scans
__device__ __forceinline__ void dscan3(float& f, float& z, float& r) {
  f *= updpp<0x111,0xF,false>(1.f,f); z += updpp<0x111,0xF,true>(0.f,z); r += updpp<0x111,0xF,true>(0.f,r);
  f *= updpp<0x112,0xF,false>(1.f,f); z += updpp<0x112,0xF,true>(0.f,z); r += updpp<0x112,0xF,true>(0.f,r);
  f *= updpp<0x114,0xF,false>(1.f,f); z += updpp<0x114,0xF,true>(0.f,z); r += updpp<0x114,0xF,true>(0.f,r);
  f *= updpp<0x118,0xF,false>(1.f,f); z += updpp<0x118,0xF,true>(0.f,z); r += updpp<0x118,0xF,true>(0.f,r);
  f *= updpp<0x142,0xA,false>(1.f,f); z += updpp<0x142,0xA,true>(0.f,z); r += updpp<0x142,0xA,true>(0.f,r);
  f *= updpp<0x143,0xC,false>(1.f,f); z += updpp<0x143,0xC,true>(0.f,z); r += updpp<0x143,0xC,true>(0.f,r);
}

// -------- K0: transpose weights + C_prev; Cp row-sums (one-time prep) -------
__global__ void k_prep(const float* __restrict__ Cp,
                       const float* __restrict__ wq, const float* __restrict__ wk,
                       const float* __restrict__ wv, const float* __restrict__ wo,
                       const float* __restrict__ rw1,
                       float* __restrict__ CpT, float* __restrict__ wqT,
                       float* __restrict__ wkT, float* __restrict__ wvT,
                       float* __restrict__ woT, float* __restrict__ rw1T,
                       float* __restrict__ cpr, float* __restrict__ cpn2) {
  int blk = blockIdx.x; int lane = threadIdx.x;
  if (blk < BB) {
    int b = blk;
    const float* rowp = Cp + (size_t)(b * DD + lane) * DD;
    float rs = 0.f, r2 = 0.f;
#pragma unroll 8
    for (int j = 0; j < DD; ++j) {
      float c = rowp[j];
      rs += c; r2 = fmaf(c, c, r2);
      CpT[(size_t)(b * DD + j) * DD + lane] = c;
    }
    cpr[b * DD + lane] = rs;
    float tot2 = dsum64(r2);
    if (lane == 0) cpn2[b] = tot2;
  } else {
    const float* src; float* dst;
    switch (blk - BB) {
      case 0: src = wq;  dst = wqT;  break;
      case 1: src = wk;  dst = wkT;  break;
      case 2: src = wv;  dst = wvT;  break;
      case 3: src = wo;  dst = woT;  break;
      default: src = rw1; dst = rw1T; break;
    }
#pragma unroll 8
    for (int f = 0; f < FF; ++f) dst[f * DD + lane] = src[lane * FF + f];
  }
}

// ---------------- K1: windowed std, one block per (b, s>=w-1) ----------------
__global__ void k_vol_std(const float* __restrict__ x, float* __restrict__ svraw) {
  int b = blockIdx.x; int s = WVOL - 1 + blockIdx.y;
  int lane = threadIdx.x; int f = lane & 31; int half = lane >> 5;
  const float* xb = x + (size_t)(b * SS) * FF + f;
  float wsum = 0.f, wsq = 0.f;
  int t0 = s - WVOL + 1 + half;
#pragma unroll 17
  for (int k = 0; k < WVOL / 2; ++k) {
    float xv = xb[(t0 + 2 * k) * FF];
    wsum += xv; wsq = fmaf(xv, xv, wsq);
  }
  wsum += __shfl_xor(wsum, 32); wsq += __shfl_xor(wsq, 32);
  float var = (wsq - wsum * wsum * (1.f / WVOL)) * (1.f / (WVOL - 1));
  float sd = sqrtf(fmaxf(var, 0.f));
  float m = dsum64(sd) * 0.5f * (1.f / FF);
  if (lane == 0) svraw[b * SS + s] = m;
}

// ---------------- K2: per-(b,s) LN + projections + gates + zc ----------------
__global__ void k_proj(const float* __restrict__ x, const float* __restrict__ m_prev,
                       const float* __restrict__ CpT,
                       const float* __restrict__ ln_in_g, const float* __restrict__ ln_in_b,
                       const float* __restrict__ wqT, const float* __restrict__ bq,
                       const float* __restrict__ wkT, const float* __restrict__ bk,
                       const float* __restrict__ wvT, const float* __restrict__ bv,
                       const float* __restrict__ wi, const float* __restrict__ bi,
                       const float* __restrict__ wf, const float* __restrict__ bf,
                       const float* __restrict__ woT, const float* __restrict__ bo,
                       const float* __restrict__ rw1T, const float* __restrict__ rd_b1,
                       const float* __restrict__ rd_g, const float* __restrict__ rd_be,
                       const float* __restrict__ rd_w2, const float* __restrict__ rd_b2,
                       float* __restrict__ qo, float* __restrict__ kno, float* __restrict__ vno,
                       float* __restrict__ iko, float* __restrict__ oo,
                       float* __restrict__ cg_a, float* __restrict__ fg_a,
                       float* __restrict__ mf_a, float* __restrict__ cks_a,
                       float* __restrict__ qsum_a, float* __restrict__ zc) {
  int bs = blockIdx.x; int b = bs / SS;
  int lane = threadIdx.x;
  __shared__ float xs[FF];
  __shared__ float ks[DD];
  float xv = (lane < FF) ? x[bs * FF + lane] : 0.f;
  float s1x = xv, s2x = xv * xv;
  dred2_32(s1x, s2x);
  if (lane < FF) {
    float mu = s1x * (1.f / FF);
    float var = s2x * (1.f / FF) - mu * mu;
    xs[lane] = (xv - mu) * rsqrtf(var + 1e-5f) * ln_in_g[lane] + ln_in_b[lane];
  }
  __syncthreads();
  int d = lane;
  float aq = bq[d], ak = bk[d], av = bv[d], ao = bo[d], at = rd_b1[d];
#pragma unroll
  for (int f = 0; f < FF; ++f) {
    float xf = xs[f];
    aq = fmaf(xf, wqT[f * DD + d], aq);
    ak = fmaf(xf, wkT[f * DD + d], ak);
    av = fmaf(xf, wvT[f * DD + d], av);
    ao = fmaf(xf, woT[f * DD + d], ao);
    at = fmaf(xf, rw1T[f * DD + d], at);
  }
  float pit = (lane < FF) ? xs[lane] * wi[lane] : 0.f;
  float pft = (lane < FF) ? xs[lane] * wf[lane] : 0.f;
  dred2_32(pit, pft);
  float itv = pit + bi[0];
  float ftv = pft + bf[0];
  float s1 = at, s2 = at * at;
  dred2(s1, s2);
  float mu = s1 * (1.f / DD);
  float var = s2 * (1.f / DD) - mu * mu;
  float tn = (at - mu) * rsqrtf(var + 1e-5f) * rd_g[d] + rd_be[d];
  float ge = 0.5f * tn * (1.f + erff(tn * 0.70710678118654752f));
  float l0 = ge * rd_w2[0 * DD + d], l1 = ge * rd_w2[1 * DD + d];
  float l2 = ge * rd_w2[2 * DD + d], l3 = ge * rd_w2[3 * DD + d];
  dred4(l0, l1, l2, l3);
  l0 += rd_b2[0]; l1 += rd_b2[1]; l2 += rd_b2[2]; l3 += rd_b2[3];
  float mx = fmaxf(fmaxf(l0, l1), fmaxf(l2, l3));
  float e0 = expf(l0 - mx), e1 = expf(l1 - mx), e2 = expf(l2 - mx), e3 = expf(l3 - mx);
  float mfv = e0 / (e0 + e1 + e2 + e3);
  float kd = ak * 0.125f;
  float kk = kd * kd, vv = av * av, qsum = aq;
  dred3(kk, vv, qsum);
  float knd = kd * (8.f / (sqrtf(kk) + 1e-12f));
  float vnd = av * (8.f / (sqrtf(vv) + 1e-6f));
  float ksum = dsum64(knd);
  float mp = fminf(fmaxf(m_prev[b], -100.f), 100.f);
  float mt = fmaxf(ftv, mp + ftv);
  float ig = expf(fminf(fmaxf(itv - mt, -15.f), 15.f));
  float fg = expf(fminf(fmaxf(ftv + mp - mt, -15.f), 15.f));
  float cg = fminf(ig, 1.f);
  qo[bs * DD + d] = aq;
  kno[bs * DD + d] = knd;
  vno[bs * DD + d] = vnd;
  iko[bs * DD + d] = ig * kd;
  oo[bs * DD + d] = 1.f / (1.f + expf(-ao));
  ks[d] = knd;
  __syncthreads();
  float acc = 0.f;
  const float* cpt = CpT + (size_t)b * DD * DD;
#pragma unroll 8
  for (int j = 0; j < DD; ++j) acc = fmaf(cpt[j * DD + d], ks[j], acc);
  float z = dsum64(vnd * acc);
  if (lane == 0) {
    cg_a[bs] = cg; fg_a[bs] = fg; mf_a[bs] = mfv;
    cks_a[bs] = cg * ksum; qsum_a[bs] = qsum;
    zc[bs] = cg * z;
  }
}

// -------- K3a: tiled GEMM over causal 32x32 (s,t) tile pairs ----------------
__global__ void k_qk(const float* __restrict__ qo, const float* __restrict__ kno,
                     const float* __restrict__ vno, const float* __restrict__ cg_a,
                     float* __restrict__ W, float* __restrict__ rho) {
  int blk = blockIdx.x; int b = blk / 136; int r = blk % 136;
  int st = 0;
  while ((st + 1) * (st + 2) / 2 <= r) ++st;
  int tt = r - st * (st + 1) / 2;
  int s0 = st * 32, t0 = tt * 32;
  int tid = threadIdx.x; int ty = tid >> 4, tx = tid & 15;
  __shared__ float qls[32][64], kls[32][64], vsl[32][64];
  __shared__ float ktl[32][68], vtl[32][68];
  __shared__ float cgl[32], sacc[32];
  {
    int col = tid & 63, rg = tid >> 6;
#pragma unroll
    for (int rr = 0; rr < 8; ++rr) {
      int row = rg * 8 + rr;
      int gi = (b * SS + s0 + row) * DD + col;
      int gj = (b * SS + t0 + row) * DD + col;
      qls[row][col] = qo[gi]; kls[row][col] = kno[gi]; vsl[row][col] = vno[gi];
      ktl[row][col] = kno[gj]; vtl[row][col] = vno[gj];
    }
    if (tid < 32) cgl[tid] = cg_a[b * SS + t0 + tid];
  }
  __syncthreads();
  float A[2][2] = {{0.f, 0.f}, {0.f, 0.f}};
  float KK[2][2] = {{0.f, 0.f}, {0.f, 0.f}};
  float VV[2][2] = {{0.f, 0.f}, {0.f, 0.f}};
  for (int k4 = 0; k4 < DD; k4 += 4) {
    float qa[2][4], ka[2][4], va[2][4], kt[2][4], vt[2][4];
#pragma unroll
    for (int i = 0; i < 2; ++i) {
      float4 t1 = *(const float4*)&qls[ty * 2 + i][k4];
      qa[i][0] = t1.x; qa[i][1] = t1.y; qa[i][2] = t1.z; qa[i][3] = t1.w;
      float4 t2 = *(const float4*)&kls[ty * 2 + i][k4];
      ka[i][0] = t2.x; ka[i][1] = t2.y; ka[i][2] = t2.z; ka[i][3] = t2.w;
      float4 t3 = *(const float4*)&vsl[ty * 2 + i][k4];
      va[i][0] = t3.x; va[i][1] = t3.y; va[i][2] = t3.z; va[i][3] = t3.w;
      float4 t4 = *(const float4*)&ktl[tx * 2 + i][k4];
      kt[i][0] = t4.x; kt[i][1] = t4.y; kt[i][2] = t4.z; kt[i][3] = t4.w;
      float4 t5 = *(const float4*)&vtl[tx * 2 + i][k4];
      vt[i][0] = t5.x; vt[i][1] = t5.y; vt[i][2] = t5.z; vt[i][3] = t5.w;
    }
#pragma unroll
    for (int kk = 0; kk < 4; ++kk)
#pragma unroll
      for (int i = 0; i < 2; ++i)
#pragma unroll
        for (int j = 0; j < 2; ++j) {
          A[i][j]  = fmaf(qa[i][kk], kt[j][kk], A[i][j]);
          KK[i][j] = fmaf(ka[i][kk], kt[j][kk], KK[i][j]);
          VV[i][j] = fmaf(va[i][kk], vt[j][kk], VV[i][j]);
        }
  }
  float cg0 = cgl[tx * 2], cg1 = cgl[tx * 2 + 1];
  int tg0 = t0 + tx * 2, tg1 = t0 + tx * 2 + 1;
#pragma unroll
  for (int i = 0; i < 2; ++i) {
    int s = s0 + ty * 2 + i;
    float w0 = (tg0 <= s) ? cg0 * A[i][0] : 0.f;
    float w1 = (tg1 <= s) ? cg1 * A[i][1] : 0.f;
    float2 wst = make_float2(w0, w1);
    *(float2*)&W[((size_t)b * SS + s) * SS + tg0] = wst;
    float wr0 = (tg0 < s) ? 2.f : (tg0 == s ? 1.f : 0.f);
    float wr1 = (tg1 < s) ? 2.f : (tg1 == s ? 1.f : 0.f);
    float rsum = dsum16(fmaf(wr0 * cg0, KK[i][0] * VV[i][0],
                             wr1 * cg1 * KK[i][1] * VV[i][1]));
    if (tx == 15) sacc[ty * 2 + i] = rsum;
  }
  __syncthreads();
  if (tid < 32) {
    int s = s0 + tid;
    atomicAdd(&rho[b * SS + s], cg_a[b * SS + s] * sacc[tid]);
  }
}

// -------- K3b: p2 = W @ vn (causal K handled by masked/zeroed W) ------------
__global__ void k_pv(const float* __restrict__ W, const float* __restrict__ vno,
                     float* __restrict__ p2) {
  int blk = blockIdx.x; int b = blk / 26; int u = blk % 26;
  int st32, c0, c1;
  if (u < 6) { st32 = u; c0 = 0; c1 = u >> 1; }
  else {
    int v = u - 6; st32 = 6 + (v >> 1);
    int nch = (st32 >> 1) + 1; int h0 = nch >> 1;
    if (v & 1) { c0 = h0; c1 = nch - 1; } else { c0 = 0; c1 = h0 - 1; }
  }
  int s0 = st32 * 32;
  int tid = threadIdx.x; int ty = tid >> 4, tx = tid & 15;
  __shared__ float wls[32][64];
  __shared__ float vls[64][64];
  float acc[2][4] = {{0.f, 0.f, 0.f, 0.f}, {0.f, 0.f, 0.f, 0.f}};
  for (int c = c0; c <= c1; ++c) {
    __syncthreads();
    int t0 = c * 64;
    int col = tid & 63, rg = tid >> 6;
#pragma unroll
    for (int rr = 0; rr < 8; ++rr) {
      int r2 = rg * 8 + rr;
      wls[r2][col] = W[((size_t)b * SS + s0 + r2) * SS + t0 + col];
    }
#pragma unroll
    for (int rr = 0; rr < 16; ++rr) {
      int t = rg * 16 + rr;
      vls[t][col] = vno[(b * SS + t0 + t) * DD + col];
    }
    __syncthreads();
    for (int k4 = 0; k4 < 64; k4 += 4) {
      float aa[2][4];
#pragma unroll
      for (int i = 0; i < 2; ++i) {
        float4 t1 = *(const float4*)&wls[ty * 2 + i][k4];
        aa[i][0] = t1.x; aa[i][1] = t1.y; aa[i][2] = t1.z; aa[i][3] = t1.w;
      }
      float bb[4][4];
#pragma unroll
      for (int kk = 0; kk < 4; ++kk) {
        float4 t2 = *(const float4*)&vls[k4 + kk][tx * 4];
        bb[kk][0] = t2.x; bb[kk][1] = t2.y; bb[kk][2] = t2.z; bb[kk][3] = t2.w;
      }
#pragma unroll
      for (int kk = 0; kk < 4; ++kk)
#pragma unroll
        for (int i = 0; i < 2; ++i)
#pragma unroll
          for (int j = 0; j < 4; ++j)
            acc[i][j] = fmaf(aa[i][kk], bb[kk][j], acc[i][j]);
    }
  }
#pragma unroll
  for (int i = 0; i < 2; ++i)
#pragma unroll
    for (int j = 0; j < 4; ++j)
      atomicAdd(&p2[(b * SS + s0 + ty * 2 + i) * DD + tx * 4 + j], acc[i][j]);
}

// ---- K4: merged: blocks 0..7 scalar scans + vol-norm; blocks 8+ chunk sums --
__global__ void k_post(const float* __restrict__ fg_a, const float* __restrict__ zc,
                       const float* __restrict__ rho, const float* __restrict__ svraw,
                       const float* __restrict__ ik, const float* __restrict__ vno,
                       const float* __restrict__ cks_a,
                       float* __restrict__ fcum, float* __restrict__ cpd,
                       float* __restrict__ sn2, float* __restrict__ sv,
                       float* __restrict__ csn, float* __restrict__ csr) {
  int blk = blockIdx.x; int lane = threadIdx.x;
  if (blk < BB) {
    int b = blk;
    float m0 = svraw[b * SS + WVOL - 1];
    float vals[8]; float part = 0.f;
#pragma unroll
    for (int c = 0; c < 8; ++c) {
      int idx = c * 64 + lane;
      float v = (idx < WVOL - 1) ? m0 : svraw[b * SS + idx];
      vals[c] = v; part += v;
    }
    float tot = dsum64(part);
    float inv = 1.f / (tot * (1.f / SS) + 1e-6f);
#pragma unroll
    for (int c = 0; c < 8; ++c) sv[b * SS + c * 64 + lane] = vals[c] * inv;
    float cf = 1.f, cz = 0.f, crr = 0.f;
    for (int c = 0; c < 8; ++c) {
      int bs = b * SS + c * 64 + lane;
      float f = fg_a[bs], z = zc[bs], r = rho[bs];
      dscan3(f, z, r);
      f *= cf; z += cz; r += crr;
      fcum[bs] = f; cpd[bs] = z; sn2[bs] = r;
      cf = rlane(f, 63); cz = rlane(z, 63); crr = rlane(r, 63);
    }
  } else {
    int blk2 = blk - BB; int b = blk2 / NCH; int w = blk2 % NCH; int d = lane;
    float na = 0.f, ra = 0.f;
#pragma unroll
    for (int t = 0; t < CH; ++t) {
      int bs = b * SS + w * CH + t;
      na += ik[bs * DD + d];
      ra = fmaf(cks_a[bs], vno[bs * DD + d], ra);
    }
    csn[blk2 * DD + d] = na; csr[blk2 * DD + d] = ra;
  }
}

// ---- K5: scan apply (blocks 0..255) + S1/S2 tables (blocks 256..4351) ------
__global__ void k_scan_apply(const float* __restrict__ ik, const float* __restrict__ vno,
                             const float* __restrict__ cks_a,
                             const float* __restrict__ csn, const float* __restrict__ csr,
                             const float* __restrict__ sv,
                             const float* __restrict__ cvec, const float* __restrict__ ln_g,
                             const float* __restrict__ ln_b, const float* __restrict__ vol_gate,
                             float* __restrict__ nacc, float* __restrict__ racc,
                             float* __restrict__ S1g, float* __restrict__ S2g) {
  int blk = blockIdx.x;
  if (blk < BB * NCH) {
    int b = blk / NCH; int w = blk % NCH; int d = threadIdx.x;
    float na = 0.f, ra = 0.f;
    for (int w2 = 0; w2 < w; ++w2) {
      na += csn[(b * NCH + w2) * DD + d];
      ra += csr[(b * NCH + w2) * DD + d];
    }
#pragma unroll
    for (int t = 0; t < CH; ++t) {
      int bs = b * SS + w * CH + t;
      na += ik[bs * DD + d];
      ra = fmaf(cks_a[bs], vno[bs * DD + d], ra);
      nacc[bs * DD + d] = na;
      racc[bs * DD + d] = ra;
    }
  } else {
    int bs = blk - BB * NCH;  // 0..BB*SS-1
    int nn = threadIdx.x;
    float cn = cvec[nn], g = ln_g[nn], be = ln_b[nn];
    float vg = 1.f / (1.f + expf(-vol_gate[nn]));
    float vol = sv[bs];
    float rden = __builtin_amdgcn_rcpf(fmaf(vg, vol, 1.f));
    float r1 = cn * g * rden, r2 = cn * be * rden;
    dred2(r1, r2);
    if (nn == 0) { S1g[bs] = r1; S2g[bs] = r2; }
  }
}

// ---- K6: SSM scan; pre-LN state, 3-way interleaved reduce, post-chunk y ----
__global__ void k_ssm(const float* __restrict__ fcum, const float* __restrict__ racc,
                      const float* __restrict__ cpr, const float* __restrict__ sv,
                      const float* __restrict__ log_lam, const float* __restrict__ log_b,
                      const float* __restrict__ cvec,
                      const float* __restrict__ log_step, const float* __restrict__ vol_gate,
                      const float* __restrict__ ln_g, const float* __restrict__ ln_b,
                      const float* __restrict__ S1g, const float* __restrict__ S2g,
                      float* __restrict__ ysT) {
  int blk = blockIdx.x; int b = blk >> 6; int i = blk & 63;
  int n = threadIdx.x;
  float st = expf(log_step[0]);
  float lam = -expf(log_lam[n]);
  float ad = (2.f + st * lam) / (2.f - st * lam);
  float bd = st * (1.f + ad) * expf(log_b[n]) * 0.5f;
  float vg = 1.f / (1.f + expf(-vol_gate[n]));
  float g = ln_g[n], be = ln_b[n], cn = cvec[n];
  float adg = ad * g, adbe = ad * be, cng = cn * g;
  float cprv = cpr[b * DD + i];
  float u[8], w[8], S1a[8], S2a[8];
#pragma unroll
  for (int c = 0; c < 8; ++c) {
    int s = c * 64 + n; int bs = b * SS + s;
    u[c] = fmaf(fcum[bs], cprv, racc[(size_t)bs * DD + i]) * (1.f / DD);
    w[c] = sv[bs];
    S1a[c] = S1g[bs]; S2a[c] = S2g[bs];
  }
  float ht = bd * rlane(u[0], 0);   // h0=0: ht_0 = bd*u_0
#pragma unroll
  for (int c = 0; c < 8; ++c) {
    float macc = 0.f, iacc = 0.f, s3acc = 0.f;
#pragma unroll 4
    for (int t2 = 0; t2 < 64; ++t2) {
      float vvol = rlane(w[c], t2);
      float rden = __builtin_amdgcn_rcpf(fmaf(vg, vvol, 1.f));  // off-chain
      float p1 = ht, p2 = ht * ht, p3 = (cng * rden) * ht;
      p1 += updpp<0x111,0xF,true>(0.f,p1); p2 += updpp<0x111,0xF,true>(0.f,p2); p3 += updpp<0x111,0xF,true>(0.f,p3);
      p1 += updpp<0x112,0xF,true>(0.f,p1); p2 += updpp<0x112,0xF,true>(0.f,p2); p3 += updpp<0x112,0xF,true>(0.f,p3);
      p1 += updpp<0x114,0xF,true>(0.f,p1); p2 += updpp<0x114,0xF,true>(0.f,p2); p3 += updpp<0x114,0xF,true>(0.f,p3);
      p1 += updpp<0x118,0xF,true>(0.f,p1); p2 += updpp<0x118,0xF,true>(0.f,p2); p3 += updpp<0x118,0xF,true>(0.f,p3);
      p1 += updpp<0x142,0xF,true>(0.f,p1); p2 += updpp<0x142,0xF,true>(0.f,p2); p3 += updpp<0x142,0xF,true>(0.f,p3);
      p1 += updpp<0x143,0xF,true>(0.f,p1); p2 += updpp<0x143,0xF,true>(0.f,p2); p3 += updpp<0x143,0xF,true>(0.f,p3);
      float s1 = rlane(p1, 63), s2v = rlane(p2, 63), s3 = rlane(p3, 63);
      float mu = s1 * (1.f / DD);
      float r2m = fmaf(-mu, s1, s2v);
      float arg = fmaxf(fmaf(r2m, 1.f / DD, 1e-5f), 1e-5f);
      float irs = __builtin_amdgcn_rsqf(arg);
      bool sel = (n == t2);
      macc = sel ? mu : macc;
      iacc = sel ? irs : iacc;
      s3acc = sel ? s3 : s3acc;
      float un = (t2 < 63) ? rlane(u[c], t2 + 1)
                           : ((c < 7) ? rlane(u[(c + 1) & 7], 0) : 0.f);
      float A = adg * rden;                    // off-chain
      float B = fmaf(adbe, rden, bd * un);     // off-chain
      ht = fmaf((ht - mu) * A, irs, B);        // ht_{t+1} = ad*hv_t + bd*u_{t+1}
    }
    float y = fmaf(iacc, fmaf(-macc, S1a[c], s3acc), S2a[c]);
    ysT[(size_t)(b * DD + i) * SS + c * 64 + n] = y;
  }
}

// ---------------- K7: final readout ----------------
__global__ void k_final(const float* __restrict__ qo, const float* __restrict__ oo,
                        const float* __restrict__ p2, const float* __restrict__ racc,
                        const float* __restrict__ nacc, const float* __restrict__ ysT,
                        const float* __restrict__ CpT, const float* __restrict__ cpr,
                        const float* __restrict__ cpn2,
                        const float* __restrict__ fcum, const float* __restrict__ cpd,
                        const float* __restrict__ sn2,
                        const float* __restrict__ mf_a, const float* __restrict__ qsum_a,
                        const float* __restrict__ n_prev,
                        const float* __restrict__ ssm_log_d, const float* __restrict__ ssm_alpha,
                        const float* __restrict__ ln_mem_g, const float* __restrict__ ln_mem_b,
                        float* __restrict__ out) {
  int bs = blockIdx.x; int b = bs / SS; int s = bs % SS;
  int i = threadIdx.x;
  __shared__ float qv[DD];
  float qi = qo[bs * DD + i];
  qv[i] = qi;
  __syncthreads();
  float P1 = 0.f;
  const float* cpt = CpT + (size_t)b * DD * DD;
#pragma unroll 8
  for (int j = 0; j < DD; ++j) P1 = fmaf(cpt[j * DD + i], qv[j], P1);
  float fc = fcum[bs];
  float p = fmaf(fc, P1, p2[bs * DD + i]);
  float r = fmaf(fc, cpr[b * DD + i], racc[bs * DD + i]);
  float R2 = fc * fc * cpn2[b] + 2.f * fc * cpd[bs] + sn2[bs];
  float al = 1.f / (1.f + expf(-ssm_alpha[0]));
  float kap = al + (1.f - al) * expf(ssm_log_d[0]);
  float mfv = mf_a[bs];
  float beta = 1.f + mfv * (kap - 1.f);
  float gam = mfv * (1.f - al);
  float y = ysT[(size_t)(b * DD + i) * SS + s];
  float nt = fmaf(fc, n_prev[b * DD + i], nacc[bs * DD + i]);
  float syr = y * r, sy2 = y * y, ndp = nt * qi;
  dred3(syr, sy2, ndp);
  float nrm2 = fmaxf(beta * beta * R2 + 2.f * beta * gam * syr + gam * gam * (float)DD * sy2, 0.f);
  float scale = 8.f / (sqrtf(nrm2) + 1e-6f);
  float denom = fmaxf(fabsf(ndp), 1.f);
  float hh = scale * (fmaf(beta, p, gam * y * qsum_a[bs])) / denom;
  float s1 = hh, s2 = hh * hh;
  dred2(s1, s2);
  float mu = s1 * (1.f / DD);
  float var = fmaxf(s2 * (1.f / DD) - mu * mu, 0.f);
  float o = (hh - mu) * rsqrtf(var + 1e-5f) * ln_mem_g[i] + ln_mem_b[i];
  out[bs * DD + i] = oo[bs * DD + i] * o;
}

extern "C" void kernel_launch(void* const* d_in, const int* in_sizes, int n_in,
                              void* d_out, int out_size, void* d_ws, size_t ws_size,
                              hipStream_t stream) {
  const float* x        = (const float*)d_in[0];
  const float* C_prev   = (const float*)d_in[1];
  const float* n_prev   = (const float*)d_in[2];
  const float* m_prev   = (const float*)d_in[3];
  const float* ln_in_g  = (const float*)d_in[4];
  const float* ln_in_b  = (const float*)d_in[5];
  const float* wq = (const float*)d_in[6];  const float* bq = (const float*)d_in[7];
  const float* wk = (const float*)d_in[8];  const float* bk = (const float*)d_in[9];
  const float* wv = (const float*)d_in[10]; const float* bv = (const float*)d_in[11];
  const float* wi = (const float*)d_in[12]; const float* bi = (const float*)d_in[13];
  const float* wf = (const float*)d_in[14]; const float* bf = (const float*)d_in[15];
  const float* wo = (const float*)d_in[16]; const float* bo = (const float*)d_in[17];
  const float* rd_w1 = (const float*)d_in[18]; const float* rd_b1 = (const float*)d_in[19];
  const float* rd_g  = (const float*)d_in[20]; const float* rd_be = (const float*)d_in[21];
  const float* rd_w2 = (const float*)d_in[22]; const float* rd_b2 = (const float*)d_in[23];
  const float* ssm_log_lam  = (const float*)d_in[24];
  const float* ssm_log_b    = (const float*)d_in[25];
  const float* ssm_c        = (const float*)d_in[26];
  const float* ssm_log_d    = (const float*)d_in[27];
  const float* ssm_log_step = (const float*)d_in[28];
  const float* ssm_vol_gate = (const float*)d_in[29];
  const float* ssm_alpha    = (const float*)d_in[30];
  const float* ssm_ln_g     = (const float*)d_in[31];
  const float* ssm_ln_b     = (const float*)d_in[32];
  const float* ln_mem_g     = (const float*)d_in[33];
  const float* ln_mem_b     = (const float*)d_in[34];
  float* out = (float*)d_out;

  float* Wsp = (float*)d_ws;
  size_t o0 = 0;
  const size_t BS = (size_t)BB * SS, BSD = BS * DD, WSZ = (size_t)BB * SS * SS;
  float* sv    = Wsp + o0; o0 += BS;
  float* svraw = Wsp + o0; o0 += BS;
  float* qo   = Wsp + o0; o0 += BSD;
  float* kno  = Wsp + o0; o0 += BSD;
  float* vno  = Wsp + o0; o0 += BSD;
  float* iko  = Wsp + o0; o0 += BSD;
  float* oo   = Wsp + o0; o0 += BSD;
  float* racc = Wsp + o0; o0 += BSD;
  float* nacc = Wsp + o0; o0 += BSD;
  float* ysT  = Wsp + o0; o0 += BSD;
  float* p2   = Wsp + o0; o0 += BSD;   // memset region start
  float* rho  = Wsp + o0; o0 += BS;
  float* Wm   = Wsp + o0; o0 += WSZ;   // memset region end
  float* cg_a = Wsp + o0; o0 += BS;
  float* fg_a = Wsp + o0; o0 += BS;
  float* mf_a = Wsp + o0; o0 += BS;
  float* cks  = Wsp + o0; o0 += BS;
  float* qsum = Wsp + o0; o0 += BS;
  float* zc   = Wsp + o0; o0 += BS;
  float* fcum = Wsp + o0; o0 += BS;
  float* cpd  = Wsp + o0; o0 += BS;
  float* sn2  = Wsp + o0; o0 += BS;
  float* S1g  = Wsp + o0; o0 += BS;
  float* S2g  = Wsp + o0; o0 += BS;
  float* cpr  = Wsp + o0; o0 += (size_t)BB * DD;
  float* cpn2 = Wsp + o0; o0 += BB;
  float* csn  = Wsp + o0; o0 += (size_t)BB * NCH * DD;
  float* csr  = Wsp + o0; o0 += (size_t)BB * NCH * DD;
  float* CpT  = Wsp + o0; o0 += (size_t)BB * DD * DD;
  float* wqT  = Wsp + o0; o0 += (size_t)FF * DD;
  float* wkT  = Wsp + o0; o0 += (size_t)FF * DD;
  float* wvT  = Wsp + o0; o0 += (size_t)FF * DD;
  float* woT  = Wsp + o0; o0 += (size_t)FF * DD;
  float* rw1T = Wsp + o0; o0 += (size_t)FF * DD;

  hipMemsetAsync(p2, 0, (BSD + BS + WSZ) * sizeof(float), stream);
  hipLaunchKernelGGL(k_prep, dim3(BB + 5), dim3(64), 0, stream,
                     C_prev, wq, wk, wv, wo, rd_w1,
                     CpT, wqT, wkT, wvT, woT, rw1T, cpr, cpn2);
  hipLaunchKernelGGL(k_vol_std, dim3(BB, SS - WVOL + 1), dim3(64), 0, stream, x, svraw);
  hipLaunchKernelGGL(k_proj, dim3(BB * SS), dim3(64), 0, stream,
                     x, m_prev, CpT, ln_in_g, ln_in_b, wqT, bq, wkT, bk, wvT, bv, wi, bi,
                     wf, bf, woT, bo, rw1T, rd_b1, rd_g, rd_be, rd_w2, rd_b2,
                     qo, kno, vno, iko, oo, cg_a, fg_a, mf_a, cks, qsum, zc);
  hipLaunchKernelGGL(k_qk, dim3(BB * 136), dim3(256), 0, stream,
                     qo, kno, vno, cg_a, Wm, rho);
  hipLaunchKernelGGL(k_pv, dim3(BB * 26), dim3(256), 0, stream, Wm, vno, p2);
  hipLaunchKernelGGL(k_post, dim3(BB + BB * NCH), dim3(64), 0, stream,
                     fg_a, zc, rho, svraw, iko, vno, cks,
                     fcum, cpd, sn2, sv, csn, csr);
  hipLaunchKernelGGL(k_scan_apply, dim3(BB * NCH + BB * SS), dim3(64), 0, stream,
                     iko, vno, cks, csn, csr, sv, ssm_c, ssm_ln_g, ssm_ln_b,
                     ssm_vol_gate, nacc, racc, S1g, S2g);
  hipLaunchKernelGGL(k_ssm, dim3(BB * DD), dim3(64), 0, stream,
                     fcum, racc, cpr, sv, ssm_log_lam, ssm_log_b, ssm_c,
                     ssm_log_step, ssm_vol_gate, ssm_ln_g, ssm_ln_b, S1g, S2g, ysT);
  hipLaunchKernelGGL(k_final, dim3(BB * SS), dim3(64), 0, stream,
                     qo, oo, p2, racc, nacc, ysT, CpT, cpr, cpn2, fcum, cpd, sn2,
                     mf_a, qsum, n_prev, ssm_log_d, ssm_alpha, ln_mem_g, ln_mem_b, out);
}